// Round 1
// baseline (1383.928 us; speedup 1.0000x reference)
//
#include <hip/hip_runtime.h>
#include <hip/hip_bf16.h>
#include <math.h>

// GETS calibrator: MoE-GCN. N nodes, E edges, C=64, F=512, FH=32, DH=16.
// Strategy: aggregate union feature X = [logits|f0|e1|f2|e2] (160d) once via CSR,
// then per-node expert matmuls + gating fused in one kernel.

#define XD 160   // aggregated feature dim
#define CC 64    // classes

// ---------------- degree counting ----------------
__global__ void k_degrees(const int* __restrict__ ei, int E,
                          int* __restrict__ deg_i, int* __restrict__ deg_dst) {
  int e = blockIdx.x * blockDim.x + threadIdx.x;
  if (e >= E) return;
  int s = ei[e], d = ei[E + e];
  atomicAdd(&deg_i[s], 1);
  atomicAdd(&deg_i[d], 1);
  atomicAdd(&deg_dst[d], 1);
}

// ---------------- 2-level exclusive scan of deg_dst -> row_start ----------------
__global__ void k_scan1(const int* __restrict__ deg, int n, int* __restrict__ bsum) {
  __shared__ int red[1024];
  int tid = threadIdx.x;
  int i = blockIdx.x * 1024 + tid;
  red[tid] = (i < n) ? deg[i] : 0;
  __syncthreads();
  for (int s = 512; s > 0; s >>= 1) {
    if (tid < s) red[tid] += red[tid + s];
    __syncthreads();
  }
  if (tid == 0) bsum[blockIdx.x] = red[0];
}

__global__ void k_scan2(int* __restrict__ bsum, int nb, int* __restrict__ row_start, int n) {
  if (threadIdx.x == 0 && blockIdx.x == 0) {
    int run = 0;
    for (int b = 0; b < nb; ++b) { int t = bsum[b]; bsum[b] = run; run += t; }
    row_start[n] = run;   // == E
  }
}

__global__ void k_scan3(const int* __restrict__ deg, int n, const int* __restrict__ bsum,
                        int* __restrict__ row_start, float* __restrict__ dinv) {
  __shared__ int sc[1024];
  int tid = threadIdx.x;
  int i = blockIdx.x * 1024 + tid;
  int v = (i < n) ? deg[i] : 0;
  sc[tid] = v;
  __syncthreads();
  for (int ofs = 1; ofs < 1024; ofs <<= 1) {
    int t = (tid >= ofs) ? sc[tid - ofs] : 0;
    __syncthreads();
    sc[tid] += t;
    __syncthreads();
  }
  if (i < n) {
    int incl = sc[tid];
    row_start[i] = incl - v + bsum[blockIdx.x];
    dinv[i] = rsqrtf((float)v + 1.0f);   // GCN deg = indeg + 1 (self loop)
  }
}

// ---------------- CSR fill (src + precomputed coef per edge) ----------------
__global__ void k_fill(const int* __restrict__ ei, int E, const int* __restrict__ row_start,
                       int* __restrict__ cursor, const float* __restrict__ dinv,
                       int* __restrict__ srcs, float* __restrict__ coefs) {
  int e = blockIdx.x * blockDim.x + threadIdx.x;
  if (e >= E) return;
  int s = ei[e], d = ei[E + e];
  int pos = row_start[d] + atomicAdd(&cursor[d], 1);
  srcs[pos] = s;
  coefs[pos] = dinv[s] * dinv[d];
}

// ---------------- fused projection GEMM: feat(n,512) @ [Wf0|Wf2|Wfg](512,96) ----------------
// BM=64 rows/block, BK=64, 256 threads; thread owns (row r=t&63, 24 cols)
__global__ __launch_bounds__(256) void k_proj(
    const float* __restrict__ feat,
    const float* __restrict__ Wf0, const float* __restrict__ bf0,
    const float* __restrict__ Wf2, const float* __restrict__ bf2,
    const float* __restrict__ Wfg, const float* __restrict__ bfg,
    float* __restrict__ X, float* __restrict__ FG, int n) {
  __shared__ float Al[64][65];
  __shared__ float Wl[64][96];
  int t = threadIdx.x;
  int r = t & 63;
  int cg = t >> 6;        // 0..3
  int c0 = cg * 24;
  int nb = blockIdx.x * 64;
  float acc[24];
#pragma unroll
  for (int j = 0; j < 24; ++j) acc[j] = 0.f;

  for (int k0 = 0; k0 < 512; k0 += 64) {
    for (int i = t; i < 64 * 64; i += 256) {
      int rr = i >> 6, kk = i & 63;
      int node = nb + rr;
      Al[rr][kk] = (node < n) ? feat[(size_t)node * 512 + k0 + kk] : 0.f;
    }
    for (int i = t; i < 64 * 96; i += 256) {
      int kk = i / 96, c = i - kk * 96;
      int kg = k0 + kk;
      float v = (c < 32) ? Wf0[kg * 32 + c]
              : (c < 64) ? Wf2[kg * 32 + (c - 32)]
                         : Wfg[kg * 32 + (c - 64)];
      Wl[kk][c] = v;
    }
    __syncthreads();
#pragma unroll 16
    for (int kk = 0; kk < 64; ++kk) {
      float a = Al[r][kk];
#pragma unroll
      for (int j = 0; j < 24; ++j) acc[j] += a * Wl[kk][c0 + j];
    }
    __syncthreads();
  }
  int node = nb + r;
  if (node < n) {
#pragma unroll
    for (int j = 0; j < 24; ++j) {
      int c = c0 + j;
      if (c < 32)       X[(size_t)node * XD + 64 + c]        = acc[j] + bf0[c];
      else if (c < 64)  X[(size_t)node * XD + 112 + (c - 32)] = acc[j] + bf2[c - 32];
      else              FG[(size_t)node * 32 + (c - 64)]      = acc[j] + bfg[c - 64];
    }
  }
}

// ---------------- build X: logits copy + degree embeddings ----------------
__global__ void k_buildx(const float* __restrict__ logits, const int* __restrict__ deg_i,
                         const float* __restrict__ Emb1, const float* __restrict__ Emb2,
                         float* __restrict__ X, int n) {
  int gid = blockIdx.x * blockDim.x + threadIdx.x;
  if (gid >= n * 64) return;
  int node = gid >> 6, l = gid & 63;
  float* xr = X + (size_t)node * XD;
  xr[l] = logits[gid];
  if (l < 16) {
    int dg = deg_i[node]; if (dg > 127) dg = 127;
    xr[96 + l]  = Emb1[dg * 16 + l];
    xr[144 + l] = Emb2[dg * 16 + l];
  }
}

// ---------------- aggregation: Z = A_hat @ X  (1 wave per dst node) ----------------
__global__ __launch_bounds__(256) void k_agg(
    const float* __restrict__ X, float* __restrict__ Z,
    const int* __restrict__ row_start, const int* __restrict__ srcs,
    const float* __restrict__ coefs, const float* __restrict__ dinv, int n) {
  int w = threadIdx.x >> 6, l = threadIdx.x & 63;
  int node = blockIdx.x * 4 + w;
  if (node >= n) return;
  int beg = row_start[node], end = row_start[node + 1];
  float a0 = 0.f, a1 = 0.f, a2 = 0.f;
  for (int i = beg; i < end; ++i) {
    int s = srcs[i];
    float c = coefs[i];
    const float* xr = X + (size_t)s * XD;
    a0 += c * xr[l];
    a1 += c * xr[64 + l];
    if (l < 32) a2 += c * xr[128 + l];
  }
  float di = dinv[node];
  float c2 = di * di;
  const float* xs = X + (size_t)node * XD;
  a0 += c2 * xs[l];
  a1 += c2 * xs[64 + l];
  if (l < 32) a2 += c2 * xs[128 + l];
  float* zr = Z + (size_t)node * XD;
  zr[l] = a0;
  zr[64 + l] = a1;
  if (l < 32) zr[128 + l] = a2;
}

// ---------------- final: experts (Z @ We + be) + gating + combine + softplus ----------------
// 256 threads = 4 waves; each wave handles 2 nodes per pass; weights staged in LDS.
__global__ __launch_bounds__(256) void k_final(
    const float* __restrict__ Z, const float* __restrict__ logits,
    const float* __restrict__ FG, const int* __restrict__ deg_i,
    const float* __restrict__ W0, const float* __restrict__ b0,
    const float* __restrict__ W1, const float* __restrict__ b1,
    const float* __restrict__ W2, const float* __restrict__ b2,
    const float* __restrict__ Embg, const float* __restrict__ wg,
    float* __restrict__ out, int n) {
  __shared__ float W0l[96 * 64];
  __shared__ float W1l[80 * 64];
  __shared__ float W2l[48 * 64];
  __shared__ float zb[4][2][XD];

  int tid = threadIdx.x;
  for (int i = tid; i < 96 * 64; i += 256) W0l[i] = W0[i];
  for (int i = tid; i < 80 * 64; i += 256) W1l[i] = W1[i];
  for (int i = tid; i < 48 * 64; i += 256) W2l[i] = W2[i];
  __syncthreads();

  int w = tid >> 6, l = tid & 63;
  // hoisted lane-constant gating weights & biases
  float wgA0 = wg[l * 3 + 0], wgA1 = wg[l * 3 + 1], wgA2 = wg[l * 3 + 2];
  float wgB0 = 0, wgB1 = 0, wgB2 = 0, wgC0 = 0, wgC1 = 0, wgC2 = 0;
  if (l < 32) { wgB0 = wg[(64 + l) * 3 + 0]; wgB1 = wg[(64 + l) * 3 + 1]; wgB2 = wg[(64 + l) * 3 + 2]; }
  if (l < 16) { wgC0 = wg[(96 + l) * 3 + 0]; wgC1 = wg[(96 + l) * 3 + 1]; wgC2 = wg[(96 + l) * 3 + 2]; }
  float b0v = b0[l], b1v = b1[l], b2v = b2[l];

  for (int g0 = blockIdx.x * 8; g0 < n; g0 += gridDim.x * 8) {
    int nbase = g0 + w * 2;
    float lgv[2], fgv[2], egv[2];
#pragma unroll
    for (int j = 0; j < 2; ++j) {
      int node = nbase + j;
      int nc = node < n ? node : n - 1;
      const float* zr = Z + (size_t)nc * XD;
      zb[w][j][l] = zr[l];
      zb[w][j][64 + l] = zr[64 + l];
      if (l < 32) zb[w][j][128 + l] = zr[128 + l];
      lgv[j] = logits[(size_t)nc * 64 + l];
      fgv[j] = (l < 32) ? FG[(size_t)nc * 32 + l] : 0.f;
      int dg = deg_i[nc]; if (dg > 127) dg = 127;
      egv[j] = (l < 16) ? Embg[dg * 16 + l] : 0.f;
    }
    __syncthreads();   // uniform across block (g0 loop uniform); also syncs zb

    float a0[2] = {0.f, 0.f}, a1[2] = {0.f, 0.f}, a2[2] = {0.f, 0.f};
    const float4* z40 = (const float4*)zb[w][0];
    const float4* z41 = (const float4*)zb[w][1];

#pragma unroll
    for (int k = 0; k < 64; k += 4) {           // logits slice: W0 + W1
      float4 q0 = z40[k >> 2], q1 = z41[k >> 2];
      const float* p0 = (const float*)&q0;
      const float* p1 = (const float*)&q1;
#pragma unroll
      for (int kk = 0; kk < 4; ++kk) {
        float w0v = W0l[(k + kk) * 64 + l];
        float w1v = W1l[(k + kk) * 64 + l];
        a0[0] += p0[kk] * w0v; a0[1] += p1[kk] * w0v;
        a1[0] += p0[kk] * w1v; a1[1] += p1[kk] * w1v;
      }
    }
#pragma unroll
    for (int k = 64; k < 96; k += 4) {          // f0 slice: W0 rows 64..95
      float4 q0 = z40[k >> 2], q1 = z41[k >> 2];
      const float* p0 = (const float*)&q0;
      const float* p1 = (const float*)&q1;
#pragma unroll
      for (int kk = 0; kk < 4; ++kk) {
        float w0v = W0l[(k + kk) * 64 + l];
        a0[0] += p0[kk] * w0v; a0[1] += p1[kk] * w0v;
      }
    }
#pragma unroll
    for (int k = 96; k < 112; k += 4) {         // e1 slice: W1 rows 64..79
      float4 q0 = z40[k >> 2], q1 = z41[k >> 2];
      const float* p0 = (const float*)&q0;
      const float* p1 = (const float*)&q1;
#pragma unroll
      for (int kk = 0; kk < 4; ++kk) {
        float w1v = W1l[(k + kk - 32) * 64 + l];
        a1[0] += p0[kk] * w1v; a1[1] += p1[kk] * w1v;
      }
    }
#pragma unroll
    for (int k = 112; k < 160; k += 4) {        // [f2|e2] slice: W2 rows 0..47
      float4 q0 = z40[k >> 2], q1 = z41[k >> 2];
      const float* p0 = (const float*)&q0;
      const float* p1 = (const float*)&q1;
#pragma unroll
      for (int kk = 0; kk < 4; ++kk) {
        float w2v = W2l[(k + kk - 112) * 64 + l];
        a2[0] += p0[kk] * w2v; a2[1] += p1[kk] * w2v;
      }
    }

    // gating: clean = gate_in @ w_gate via lane-partial + wave reduce
    float pp0[2], pp1[2], pp2[2];
#pragma unroll
    for (int j = 0; j < 2; ++j) {
      pp0[j] = lgv[j] * wgA0 + fgv[j] * wgB0 + egv[j] * wgC0;
      pp1[j] = lgv[j] * wgA1 + fgv[j] * wgB1 + egv[j] * wgC1;
      pp2[j] = lgv[j] * wgA2 + fgv[j] * wgB2 + egv[j] * wgC2;
#pragma unroll
      for (int m = 32; m > 0; m >>= 1) {
        pp0[j] += __shfl_xor(pp0[j], m);
        pp1[j] += __shfl_xor(pp1[j], m);
        pp2[j] += __shfl_xor(pp2[j], m);
      }
    }

#pragma unroll
    for (int j = 0; j < 2; ++j) {
      int node = nbase + j;
      float v0 = a0[j] + b0v, v1 = a1[j] + b1v, v2 = a2[j] + b2v;
      float c0 = pp0[j], c1 = pp1[j], c2 = pp2[j];
      // top-2 of 3 (ties -> lower index, matching lax.top_k)
      int i0 = 0; float t0 = c0;
      if (c1 > t0) { t0 = c1; i0 = 1; }
      if (c2 > t0) { t0 = c2; i0 = 2; }
      float t1 = -3.4e38f; int i1 = 0;
      if (i0 != 0) { t1 = c0; i1 = 0; }
      if (i0 != 1 && c1 > t1) { t1 = c1; i1 = 1; }
      if (i0 != 2 && c2 > t1) { t1 = c2; i1 = 2; }
      float e1v = expf(t1 - t0);
      float gsum = 1.0f + e1v;
      float gg0 = 1.0f / gsum, gg1 = e1v / gsum;
      float y0s = (i0 == 0) ? v0 : (i0 == 1) ? v1 : v2;
      float y1s = (i1 == 0) ? v0 : (i1 == 1) ? v1 : v2;
      float comb = gg0 * y0s + gg1 * y1s;
      // softplus, stable
      float sp = fmaxf(comb, 0.f) + log1pf(expf(-fabsf(comb)));
      if (node < n) out[(size_t)node * 64 + l] = lgv[j] * sp;
    }
    __syncthreads();   // protect zb before next pass staging
  }
}

extern "C" void kernel_launch(void* const* d_in, const int* in_sizes, int n_in,
                              void* d_out, int out_size, void* d_ws, size_t ws_size,
                              hipStream_t stream) {
  const float* logits = (const float*)d_in[0];
  const float* feat   = (const float*)d_in[1];
  const int*   ei     = (const int*)d_in[2];
  const float* Wf0 = (const float*)d_in[3];
  const float* bf0 = (const float*)d_in[4];
  const float* W0  = (const float*)d_in[5];
  const float* b0  = (const float*)d_in[6];
  const float* Emb1= (const float*)d_in[7];
  const float* W1  = (const float*)d_in[8];
  const float* b1  = (const float*)d_in[9];
  const float* Wf2 = (const float*)d_in[10];
  const float* bf2 = (const float*)d_in[11];
  const float* Emb2= (const float*)d_in[12];
  const float* W2  = (const float*)d_in[13];
  const float* b2  = (const float*)d_in[14];
  const float* Wfg = (const float*)d_in[15];
  const float* bfg = (const float*)d_in[16];
  const float* Embg= (const float*)d_in[17];
  const float* wg  = (const float*)d_in[18];

  int n = in_sizes[0] / 64;
  int E = in_sizes[2] / 2;

  char* base = (char*)d_ws;
  size_t off = 0;
  auto alloc = [&](size_t bytes) -> void* {
    void* p = base + off;
    off += bytes;
    off = (off + 255) & ~(size_t)255;
    return p;
  };
  int*   deg_i     = (int*)alloc((size_t)n * 4);
  int*   deg_dst   = (int*)alloc((size_t)n * 4);
  int*   cursor    = (int*)alloc((size_t)n * 4);
  size_t zero_bytes = off;                 // deg_i + deg_dst + cursor
  int*   row_start = (int*)alloc(((size_t)n + 1) * 4);
  int*   bsum      = (int*)alloc(1024 * 4);
  float* dinv      = (float*)alloc((size_t)n * 4);
  int*   srcs      = (int*)alloc((size_t)E * 4);
  float* coefs     = (float*)alloc((size_t)E * 4);
  float* FG        = (float*)alloc((size_t)n * 32 * 4);
  float* X         = (float*)alloc((size_t)n * XD * 4);
  float* Z         = (float*)alloc((size_t)n * XD * 4);
  (void)ws_size;

  hipMemsetAsync(base, 0, zero_bytes, stream);

  int nb_scan = (n + 1023) / 1024;
  k_degrees<<<(E + 255) / 256, 256, 0, stream>>>(ei, E, deg_i, deg_dst);
  k_scan1<<<nb_scan, 1024, 0, stream>>>(deg_dst, n, bsum);
  k_scan2<<<1, 64, 0, stream>>>(bsum, nb_scan, row_start, n);
  k_scan3<<<nb_scan, 1024, 0, stream>>>(deg_dst, n, bsum, row_start, dinv);
  k_proj<<<(n + 63) / 64, 256, 0, stream>>>(feat, Wf0, bf0, Wf2, bf2, Wfg, bfg, X, FG, n);
  k_buildx<<<((size_t)n * 64 + 255) / 256, 256, 0, stream>>>(logits, deg_i, Emb1, Emb2, X, n);
  k_fill<<<(E + 255) / 256, 256, 0, stream>>>(ei, E, row_start, cursor, dinv, srcs, coefs);
  k_agg<<<(n + 3) / 4, 256, 0, stream>>>(X, Z, row_start, srcs, coefs, dinv, n);
  k_final<<<512, 256, 0, stream>>>(Z, logits, FG, deg_i, W0, b0, W1, b1, W2, b2,
                                   Embg, wg, (float*)d_out, n);
}

// Round 2
// 1068.338 us; speedup vs baseline: 1.2954x; 1.2954x over previous
//
#include <hip/hip_runtime.h>
#include <hip/hip_bf16.h>
#include <math.h>

// GETS calibrator: MoE-GCN. N nodes, E edges, C=64, F=512, FH=32, DH=16.
// Strategy: aggregate union feature X = [logits|f0|e1|f2|e2] (160d) once via CSR,
// then per-node expert matmuls + gating fused in one kernel.
// R2: k_proj rewritten as register-tiled fp32 GEMM (4x12 micro-tile, b128 LDS reads)
//     -- R1 version was LDS-read-bound (25 scalar ds_read per 24 FMA).

#define XD 160   // aggregated feature dim
#define CC 64    // classes

// ---------------- degree counting ----------------
__global__ void k_degrees(const int* __restrict__ ei, int E,
                          int* __restrict__ deg_i, int* __restrict__ deg_dst) {
  int e = blockIdx.x * blockDim.x + threadIdx.x;
  if (e >= E) return;
  int s = ei[e], d = ei[E + e];
  atomicAdd(&deg_i[s], 1);
  atomicAdd(&deg_i[d], 1);
  atomicAdd(&deg_dst[d], 1);
}

// ---------------- 2-level exclusive scan of deg_dst -> row_start ----------------
__global__ void k_scan1(const int* __restrict__ deg, int n, int* __restrict__ bsum) {
  __shared__ int red[1024];
  int tid = threadIdx.x;
  int i = blockIdx.x * 1024 + tid;
  red[tid] = (i < n) ? deg[i] : 0;
  __syncthreads();
  for (int s = 512; s > 0; s >>= 1) {
    if (tid < s) red[tid] += red[tid + s];
    __syncthreads();
  }
  if (tid == 0) bsum[blockIdx.x] = red[0];
}

__global__ void k_scan2(int* __restrict__ bsum, int nb, int* __restrict__ row_start, int n) {
  if (threadIdx.x == 0 && blockIdx.x == 0) {
    int run = 0;
    for (int b = 0; b < nb; ++b) { int t = bsum[b]; bsum[b] = run; run += t; }
    row_start[n] = run;   // == E
  }
}

__global__ void k_scan3(const int* __restrict__ deg, int n, const int* __restrict__ bsum,
                        int* __restrict__ row_start, float* __restrict__ dinv) {
  __shared__ int sc[1024];
  int tid = threadIdx.x;
  int i = blockIdx.x * 1024 + tid;
  int v = (i < n) ? deg[i] : 0;
  sc[tid] = v;
  __syncthreads();
  for (int ofs = 1; ofs < 1024; ofs <<= 1) {
    int t = (tid >= ofs) ? sc[tid - ofs] : 0;
    __syncthreads();
    sc[tid] += t;
    __syncthreads();
  }
  if (i < n) {
    int incl = sc[tid];
    row_start[i] = incl - v + bsum[blockIdx.x];
    dinv[i] = rsqrtf((float)v + 1.0f);   // GCN deg = indeg + 1 (self loop)
  }
}

// ---------------- CSR fill (src + precomputed coef per edge) ----------------
__global__ void k_fill(const int* __restrict__ ei, int E, const int* __restrict__ row_start,
                       int* __restrict__ cursor, const float* __restrict__ dinv,
                       int* __restrict__ srcs, float* __restrict__ coefs) {
  int e = blockIdx.x * blockDim.x + threadIdx.x;
  if (e >= E) return;
  int s = ei[e], d = ei[E + e];
  int pos = row_start[d] + atomicAdd(&cursor[d], 1);
  srcs[pos] = s;
  coefs[pos] = dinv[s] * dinv[d];
}

// ---------------- fused projection GEMM: feat(n,512) @ [Wf0|Wf2|Wfg](512,96) ----------------
// BM=128 rows/block, BK=32, 256 threads; thread micro-tile = 4 rows x 12 cols.
// A staged transposed (Al[kk][row]) so per-kk reads are ds_read_b128.
#define PBM 128
#define PBK 32
#define PSTRA 132   // LDS stride for A-tile rows: 132*4B = 528B, 16B-aligned

__global__ __launch_bounds__(256) void k_proj(
    const float* __restrict__ feat,
    const float* __restrict__ Wf0, const float* __restrict__ bf0,
    const float* __restrict__ Wf2, const float* __restrict__ bf2,
    const float* __restrict__ Wfg, const float* __restrict__ bfg,
    float* __restrict__ X, float* __restrict__ FG, int n) {
  __shared__ float Al[PBK][PSTRA];   // [kk][row], row 0..127
  __shared__ float Wl[PBK][96];      // [kk][col], row stride 384B (16B-aligned)
  int t = threadIdx.x;
  int lr = t & 31;            // row-group 0..31
  int cg = t >> 5;            // col-group 0..7
  int r0 = lr * 4;
  int c0 = cg * 12;
  int nb = blockIdx.x * PBM;
  float acc[4][12];
#pragma unroll
  for (int i = 0; i < 4; ++i)
#pragma unroll
    for (int j = 0; j < 12; ++j) acc[i][j] = 0.f;

  for (int k0 = 0; k0 < 512; k0 += PBK) {
    // stage A: 128x32 floats = 1024 float4 loads; 4 per thread
#pragma unroll
    for (int q = 0; q < 4; ++q) {
      int flat4 = q * 256 + t;
      int row = flat4 >> 3;          // 8 float4 per row
      int kk = (flat4 & 7) * 4;
      int node = nb + row;
      float4 v = make_float4(0.f, 0.f, 0.f, 0.f);
      if (node < n) v = *(const float4*)&feat[(size_t)node * 512 + k0 + kk];
      Al[kk + 0][row] = v.x;
      Al[kk + 1][row] = v.y;
      Al[kk + 2][row] = v.z;
      Al[kk + 3][row] = v.w;
    }
    // stage W: 32x96 = 768 float4; 3 per thread (each float4 within one source matrix)
#pragma unroll
    for (int q = 0; q < 3; ++q) {
      int flat4 = q * 256 + t;
      int kk = flat4 / 24;
      int cpos = (flat4 - kk * 24) * 4;
      int kg = k0 + kk;
      float4 v;
      if (cpos < 32)      v = *(const float4*)&Wf0[kg * 32 + cpos];
      else if (cpos < 64) v = *(const float4*)&Wf2[kg * 32 + (cpos - 32)];
      else                v = *(const float4*)&Wfg[kg * 32 + (cpos - 64)];
      *(float4*)&Wl[kk][cpos] = v;
    }
    __syncthreads();
#pragma unroll 8
    for (int kk = 0; kk < PBK; ++kk) {
      float4 av = *(const float4*)&Al[kk][r0];
      float4 w0 = *(const float4*)&Wl[kk][c0];
      float4 w1 = *(const float4*)&Wl[kk][c0 + 4];
      float4 w2 = *(const float4*)&Wl[kk][c0 + 8];
      const float* ap = (const float*)&av;
      float wv[12];
      *(float4*)&wv[0] = w0; *(float4*)&wv[4] = w1; *(float4*)&wv[8] = w2;
#pragma unroll
      for (int i = 0; i < 4; ++i)
#pragma unroll
        for (int j = 0; j < 12; ++j) acc[i][j] += ap[i] * wv[j];
    }
    __syncthreads();
  }

  // epilogue: add bias, scatter to X / FG
#pragma unroll
  for (int i = 0; i < 4; ++i) {
    int node = nb + r0 + i;
    if (node >= n) break;
    float* xr = X + (size_t)node * XD;
    float* fg = FG + (size_t)node * 32;
#pragma unroll
    for (int j = 0; j < 12; ++j) {
      int c = c0 + j;
      if (c < 32)       xr[64 + c]         = acc[i][j] + bf0[c];
      else if (c < 64)  xr[112 + (c - 32)] = acc[i][j] + bf2[c - 32];
      else              fg[c - 64]         = acc[i][j] + bfg[c - 64];
    }
  }
}

// ---------------- build X: logits copy + degree embeddings ----------------
__global__ void k_buildx(const float* __restrict__ logits, const int* __restrict__ deg_i,
                         const float* __restrict__ Emb1, const float* __restrict__ Emb2,
                         float* __restrict__ X, int n) {
  int gid = blockIdx.x * blockDim.x + threadIdx.x;
  if (gid >= n * 64) return;
  int node = gid >> 6, l = gid & 63;
  float* xr = X + (size_t)node * XD;
  xr[l] = logits[gid];
  if (l < 16) {
    int dg = deg_i[node]; if (dg > 127) dg = 127;
    xr[96 + l]  = Emb1[dg * 16 + l];
    xr[144 + l] = Emb2[dg * 16 + l];
  }
}

// ---------------- aggregation: Z = A_hat @ X  (1 wave per dst node) ----------------
__global__ __launch_bounds__(256) void k_agg(
    const float* __restrict__ X, float* __restrict__ Z,
    const int* __restrict__ row_start, const int* __restrict__ srcs,
    const float* __restrict__ coefs, const float* __restrict__ dinv, int n) {
  int w = threadIdx.x >> 6, l = threadIdx.x & 63;
  int node = blockIdx.x * 4 + w;
  if (node >= n) return;
  int beg = row_start[node], end = row_start[node + 1];
  float a0 = 0.f, a1 = 0.f, a2 = 0.f;
  for (int i = beg; i < end; ++i) {
    int s = srcs[i];
    float c = coefs[i];
    const float* xr = X + (size_t)s * XD;
    a0 += c * xr[l];
    a1 += c * xr[64 + l];
    if (l < 32) a2 += c * xr[128 + l];
  }
  float di = dinv[node];
  float c2 = di * di;
  const float* xs = X + (size_t)node * XD;
  a0 += c2 * xs[l];
  a1 += c2 * xs[64 + l];
  if (l < 32) a2 += c2 * xs[128 + l];
  float* zr = Z + (size_t)node * XD;
  zr[l] = a0;
  zr[64 + l] = a1;
  if (l < 32) zr[128 + l] = a2;
}

// ---------------- final: experts (Z @ We + be) + gating + combine + softplus ----------------
__global__ __launch_bounds__(256) void k_final(
    const float* __restrict__ Z, const float* __restrict__ logits,
    const float* __restrict__ FG, const int* __restrict__ deg_i,
    const float* __restrict__ W0, const float* __restrict__ b0,
    const float* __restrict__ W1, const float* __restrict__ b1,
    const float* __restrict__ W2, const float* __restrict__ b2,
    const float* __restrict__ Embg, const float* __restrict__ wg,
    float* __restrict__ out, int n) {
  __shared__ float W0l[96 * 64];
  __shared__ float W1l[80 * 64];
  __shared__ float W2l[48 * 64];
  __shared__ float zb[4][2][XD];

  int tid = threadIdx.x;
  for (int i = tid; i < 96 * 64; i += 256) W0l[i] = W0[i];
  for (int i = tid; i < 80 * 64; i += 256) W1l[i] = W1[i];
  for (int i = tid; i < 48 * 64; i += 256) W2l[i] = W2[i];
  __syncthreads();

  int w = tid >> 6, l = tid & 63;
  float wgA0 = wg[l * 3 + 0], wgA1 = wg[l * 3 + 1], wgA2 = wg[l * 3 + 2];
  float wgB0 = 0, wgB1 = 0, wgB2 = 0, wgC0 = 0, wgC1 = 0, wgC2 = 0;
  if (l < 32) { wgB0 = wg[(64 + l) * 3 + 0]; wgB1 = wg[(64 + l) * 3 + 1]; wgB2 = wg[(64 + l) * 3 + 2]; }
  if (l < 16) { wgC0 = wg[(96 + l) * 3 + 0]; wgC1 = wg[(96 + l) * 3 + 1]; wgC2 = wg[(96 + l) * 3 + 2]; }
  float b0v = b0[l], b1v = b1[l], b2v = b2[l];

  for (int g0 = blockIdx.x * 8; g0 < n; g0 += gridDim.x * 8) {
    int nbase = g0 + w * 2;
    float lgv[2], fgv[2], egv[2];
#pragma unroll
    for (int j = 0; j < 2; ++j) {
      int node = nbase + j;
      int nc = node < n ? node : n - 1;
      const float* zr = Z + (size_t)nc * XD;
      zb[w][j][l] = zr[l];
      zb[w][j][64 + l] = zr[64 + l];
      if (l < 32) zb[w][j][128 + l] = zr[128 + l];
      lgv[j] = logits[(size_t)nc * 64 + l];
      fgv[j] = (l < 32) ? FG[(size_t)nc * 32 + l] : 0.f;
      int dg = deg_i[nc]; if (dg > 127) dg = 127;
      egv[j] = (l < 16) ? Embg[dg * 16 + l] : 0.f;
    }
    __syncthreads();

    float a0[2] = {0.f, 0.f}, a1[2] = {0.f, 0.f}, a2[2] = {0.f, 0.f};
    const float4* z40 = (const float4*)zb[w][0];
    const float4* z41 = (const float4*)zb[w][1];

#pragma unroll
    for (int k = 0; k < 64; k += 4) {
      float4 q0 = z40[k >> 2], q1 = z41[k >> 2];
      const float* p0 = (const float*)&q0;
      const float* p1 = (const float*)&q1;
#pragma unroll
      for (int kk = 0; kk < 4; ++kk) {
        float w0v = W0l[(k + kk) * 64 + l];
        float w1v = W1l[(k + kk) * 64 + l];
        a0[0] += p0[kk] * w0v; a0[1] += p1[kk] * w0v;
        a1[0] += p0[kk] * w1v; a1[1] += p1[kk] * w1v;
      }
    }
#pragma unroll
    for (int k = 64; k < 96; k += 4) {
      float4 q0 = z40[k >> 2], q1 = z41[k >> 2];
      const float* p0 = (const float*)&q0;
      const float* p1 = (const float*)&q1;
#pragma unroll
      for (int kk = 0; kk < 4; ++kk) {
        float w0v = W0l[(k + kk) * 64 + l];
        a0[0] += p0[kk] * w0v; a0[1] += p1[kk] * w0v;
      }
    }
#pragma unroll
    for (int k = 96; k < 112; k += 4) {
      float4 q0 = z40[k >> 2], q1 = z41[k >> 2];
      const float* p0 = (const float*)&q0;
      const float* p1 = (const float*)&q1;
#pragma unroll
      for (int kk = 0; kk < 4; ++kk) {
        float w1v = W1l[(k + kk - 32) * 64 + l];
        a1[0] += p0[kk] * w1v; a1[1] += p1[kk] * w1v;
      }
    }
#pragma unroll
    for (int k = 112; k < 160; k += 4) {
      float4 q0 = z40[k >> 2], q1 = z41[k >> 2];
      const float* p0 = (const float*)&q0;
      const float* p1 = (const float*)&q1;
#pragma unroll
      for (int kk = 0; kk < 4; ++kk) {
        float w2v = W2l[(k + kk - 112) * 64 + l];
        a2[0] += p0[kk] * w2v; a2[1] += p1[kk] * w2v;
      }
    }

    float pp0[2], pp1[2], pp2[2];
#pragma unroll
    for (int j = 0; j < 2; ++j) {
      pp0[j] = lgv[j] * wgA0 + fgv[j] * wgB0 + egv[j] * wgC0;
      pp1[j] = lgv[j] * wgA1 + fgv[j] * wgB1 + egv[j] * wgC1;
      pp2[j] = lgv[j] * wgA2 + fgv[j] * wgB2 + egv[j] * wgC2;
#pragma unroll
      for (int m = 32; m > 0; m >>= 1) {
        pp0[j] += __shfl_xor(pp0[j], m);
        pp1[j] += __shfl_xor(pp1[j], m);
        pp2[j] += __shfl_xor(pp2[j], m);
      }
    }

#pragma unroll
    for (int j = 0; j < 2; ++j) {
      int node = nbase + j;
      float v0 = a0[j] + b0v, v1 = a1[j] + b1v, v2 = a2[j] + b2v;
      float c0 = pp0[j], c1 = pp1[j], c2 = pp2[j];
      int i0 = 0; float t0 = c0;
      if (c1 > t0) { t0 = c1; i0 = 1; }
      if (c2 > t0) { t0 = c2; i0 = 2; }
      float t1 = -3.4e38f; int i1 = 0;
      if (i0 != 0) { t1 = c0; i1 = 0; }
      if (i0 != 1 && c1 > t1) { t1 = c1; i1 = 1; }
      if (i0 != 2 && c2 > t1) { t1 = c2; i1 = 2; }
      float e1v = expf(t1 - t0);
      float gsum = 1.0f + e1v;
      float gg0 = 1.0f / gsum, gg1 = e1v / gsum;
      float y0s = (i0 == 0) ? v0 : (i0 == 1) ? v1 : v2;
      float y1s = (i1 == 0) ? v0 : (i1 == 1) ? v1 : v2;
      float comb = gg0 * y0s + gg1 * y1s;
      float sp = fmaxf(comb, 0.f) + log1pf(expf(-fabsf(comb)));
      if (node < n) out[(size_t)node * 64 + l] = lgv[j] * sp;
    }
    __syncthreads();
  }
}

extern "C" void kernel_launch(void* const* d_in, const int* in_sizes, int n_in,
                              void* d_out, int out_size, void* d_ws, size_t ws_size,
                              hipStream_t stream) {
  const float* logits = (const float*)d_in[0];
  const float* feat   = (const float*)d_in[1];
  const int*   ei     = (const int*)d_in[2];
  const float* Wf0 = (const float*)d_in[3];
  const float* bf0 = (const float*)d_in[4];
  const float* W0  = (const float*)d_in[5];
  const float* b0  = (const float*)d_in[6];
  const float* Emb1= (const float*)d_in[7];
  const float* W1  = (const float*)d_in[8];
  const float* b1  = (const float*)d_in[9];
  const float* Wf2 = (const float*)d_in[10];
  const float* bf2 = (const float*)d_in[11];
  const float* Emb2= (const float*)d_in[12];
  const float* W2  = (const float*)d_in[13];
  const float* b2  = (const float*)d_in[14];
  const float* Wfg = (const float*)d_in[15];
  const float* bfg = (const float*)d_in[16];
  const float* Embg= (const float*)d_in[17];
  const float* wg  = (const float*)d_in[18];

  int n = in_sizes[0] / 64;
  int E = in_sizes[2] / 2;

  char* base = (char*)d_ws;
  size_t off = 0;
  auto alloc = [&](size_t bytes) -> void* {
    void* p = base + off;
    off += bytes;
    off = (off + 255) & ~(size_t)255;
    return p;
  };
  int*   deg_i     = (int*)alloc((size_t)n * 4);
  int*   deg_dst   = (int*)alloc((size_t)n * 4);
  int*   cursor    = (int*)alloc((size_t)n * 4);
  size_t zero_bytes = off;                 // deg_i + deg_dst + cursor
  int*   row_start = (int*)alloc(((size_t)n + 1) * 4);
  int*   bsum      = (int*)alloc(1024 * 4);
  float* dinv      = (float*)alloc((size_t)n * 4);
  int*   srcs      = (int*)alloc((size_t)E * 4);
  float* coefs     = (float*)alloc((size_t)E * 4);
  float* FG        = (float*)alloc((size_t)n * 32 * 4);
  float* X         = (float*)alloc((size_t)n * XD * 4);
  float* Z         = (float*)alloc((size_t)n * XD * 4);
  (void)ws_size;

  hipMemsetAsync(base, 0, zero_bytes, stream);

  int nb_scan = (n + 1023) / 1024;
  k_degrees<<<(E + 255) / 256, 256, 0, stream>>>(ei, E, deg_i, deg_dst);
  k_scan1<<<nb_scan, 1024, 0, stream>>>(deg_dst, n, bsum);
  k_scan2<<<1, 64, 0, stream>>>(bsum, nb_scan, row_start, n);
  k_scan3<<<nb_scan, 1024, 0, stream>>>(deg_dst, n, bsum, row_start, dinv);
  k_proj<<<(n + PBM - 1) / PBM, 256, 0, stream>>>(feat, Wf0, bf0, Wf2, bf2, Wfg, bfg, X, FG, n);
  k_buildx<<<((size_t)n * 64 + 255) / 256, 256, 0, stream>>>(logits, deg_i, Emb1, Emb2, X, n);
  k_fill<<<(E + 255) / 256, 256, 0, stream>>>(ei, E, row_start, cursor, dinv, srcs, coefs);
  k_agg<<<(n + 3) / 4, 256, 0, stream>>>(X, Z, row_start, srcs, coefs, dinv, n);
  k_final<<<512, 256, 0, stream>>>(Z, logits, FG, deg_i, W0, b0, W1, b1, W2, b2,
                                   Embg, wg, (float*)d_out, n);
}

// Round 3
// 921.162 us; speedup vs baseline: 1.5024x; 1.1598x over previous
//
#include <hip/hip_runtime.h>
#include <hip/hip_bf16.h>
#include <math.h>

// GETS calibrator: MoE-GCN. N nodes, E edges, C=64, F=512, FH=32, DH=16.
// R3: k_final rewritten lane=node with W via uniform scalar loads (SGPR broadcast),
//     comb[64] in VGPRs, gate-prescaled z, no LDS. Z stored transposed (Zt[chunk][node][4])
//     by k_agg so k_final's per-lane z reads are coalesced.

#define XD 160   // aggregated feature dim
#define CC 64    // classes

// ---------------- degree counting ----------------
__global__ void k_degrees(const int* __restrict__ ei, int E,
                          int* __restrict__ deg_i, int* __restrict__ deg_dst) {
  int e = blockIdx.x * blockDim.x + threadIdx.x;
  if (e >= E) return;
  int s = ei[e], d = ei[E + e];
  atomicAdd(&deg_i[s], 1);
  atomicAdd(&deg_i[d], 1);
  atomicAdd(&deg_dst[d], 1);
}

// ---------------- 2-level exclusive scan of deg_dst -> row_start ----------------
__global__ void k_scan1(const int* __restrict__ deg, int n, int* __restrict__ bsum) {
  __shared__ int red[1024];
  int tid = threadIdx.x;
  int i = blockIdx.x * 1024 + tid;
  red[tid] = (i < n) ? deg[i] : 0;
  __syncthreads();
  for (int s = 512; s > 0; s >>= 1) {
    if (tid < s) red[tid] += red[tid + s];
    __syncthreads();
  }
  if (tid == 0) bsum[blockIdx.x] = red[0];
}

__global__ void k_scan2(int* __restrict__ bsum, int nb, int* __restrict__ row_start, int n) {
  if (threadIdx.x == 0 && blockIdx.x == 0) {
    int run = 0;
    for (int b = 0; b < nb; ++b) { int t = bsum[b]; bsum[b] = run; run += t; }
    row_start[n] = run;   // == E
  }
}

__global__ void k_scan3(const int* __restrict__ deg, int n, const int* __restrict__ bsum,
                        int* __restrict__ row_start, float* __restrict__ dinv) {
  __shared__ int sc[1024];
  int tid = threadIdx.x;
  int i = blockIdx.x * 1024 + tid;
  int v = (i < n) ? deg[i] : 0;
  sc[tid] = v;
  __syncthreads();
  for (int ofs = 1; ofs < 1024; ofs <<= 1) {
    int t = (tid >= ofs) ? sc[tid - ofs] : 0;
    __syncthreads();
    sc[tid] += t;
    __syncthreads();
  }
  if (i < n) {
    int incl = sc[tid];
    row_start[i] = incl - v + bsum[blockIdx.x];
    dinv[i] = rsqrtf((float)v + 1.0f);   // GCN deg = indeg + 1 (self loop)
  }
}

// ---------------- CSR fill (src + precomputed coef per edge) ----------------
__global__ void k_fill(const int* __restrict__ ei, int E, const int* __restrict__ row_start,
                       int* __restrict__ cursor, const float* __restrict__ dinv,
                       int* __restrict__ srcs, float* __restrict__ coefs) {
  int e = blockIdx.x * blockDim.x + threadIdx.x;
  if (e >= E) return;
  int s = ei[e], d = ei[E + e];
  int pos = row_start[d] + atomicAdd(&cursor[d], 1);
  srcs[pos] = s;
  coefs[pos] = dinv[s] * dinv[d];
}

// ---------------- fused projection GEMM: feat(n,512) @ [Wf0|Wf2|Wfg](512,96) ----------------
#define PBM 128
#define PBK 32
#define PSTRA 132

__global__ __launch_bounds__(256) void k_proj(
    const float* __restrict__ feat,
    const float* __restrict__ Wf0, const float* __restrict__ bf0,
    const float* __restrict__ Wf2, const float* __restrict__ bf2,
    const float* __restrict__ Wfg, const float* __restrict__ bfg,
    float* __restrict__ X, float* __restrict__ FG, int n) {
  __shared__ float Al[PBK][PSTRA];   // [kk][row]
  __shared__ float Wl[PBK][96];      // [kk][col]
  int t = threadIdx.x;
  int lr = t & 31;
  int cg = t >> 5;
  int r0 = lr * 4;
  int c0 = cg * 12;
  int nb = blockIdx.x * PBM;
  float acc[4][12];
#pragma unroll
  for (int i = 0; i < 4; ++i)
#pragma unroll
    for (int j = 0; j < 12; ++j) acc[i][j] = 0.f;

  for (int k0 = 0; k0 < 512; k0 += PBK) {
#pragma unroll
    for (int q = 0; q < 4; ++q) {
      int flat4 = q * 256 + t;
      int row = flat4 >> 3;
      int kk = (flat4 & 7) * 4;
      int node = nb + row;
      float4 v = make_float4(0.f, 0.f, 0.f, 0.f);
      if (node < n) v = *(const float4*)&feat[(size_t)node * 512 + k0 + kk];
      Al[kk + 0][row] = v.x;
      Al[kk + 1][row] = v.y;
      Al[kk + 2][row] = v.z;
      Al[kk + 3][row] = v.w;
    }
#pragma unroll
    for (int q = 0; q < 3; ++q) {
      int flat4 = q * 256 + t;
      int kk = flat4 / 24;
      int cpos = (flat4 - kk * 24) * 4;
      int kg = k0 + kk;
      float4 v;
      if (cpos < 32)      v = *(const float4*)&Wf0[kg * 32 + cpos];
      else if (cpos < 64) v = *(const float4*)&Wf2[kg * 32 + (cpos - 32)];
      else                v = *(const float4*)&Wfg[kg * 32 + (cpos - 64)];
      *(float4*)&Wl[kk][cpos] = v;
    }
    __syncthreads();
#pragma unroll 8
    for (int kk = 0; kk < PBK; ++kk) {
      float4 av = *(const float4*)&Al[kk][r0];
      float4 w0 = *(const float4*)&Wl[kk][c0];
      float4 w1 = *(const float4*)&Wl[kk][c0 + 4];
      float4 w2 = *(const float4*)&Wl[kk][c0 + 8];
      const float* ap = (const float*)&av;
      float wv[12];
      *(float4*)&wv[0] = w0; *(float4*)&wv[4] = w1; *(float4*)&wv[8] = w2;
#pragma unroll
      for (int i = 0; i < 4; ++i)
#pragma unroll
        for (int j = 0; j < 12; ++j) acc[i][j] += ap[i] * wv[j];
    }
    __syncthreads();
  }

#pragma unroll
  for (int i = 0; i < 4; ++i) {
    int node = nb + r0 + i;
    if (node >= n) break;
    float* xr = X + (size_t)node * XD;
    float* fg = FG + (size_t)node * 32;
#pragma unroll
    for (int j = 0; j < 12; ++j) {
      int c = c0 + j;
      if (c < 32)       xr[64 + c]         = acc[i][j] + bf0[c];
      else if (c < 64)  xr[112 + (c - 32)] = acc[i][j] + bf2[c - 32];
      else              fg[c - 64]         = acc[i][j] + bfg[c - 64];
    }
  }
}

// ---------------- build X: logits copy + degree embeddings ----------------
__global__ void k_buildx(const float* __restrict__ logits, const int* __restrict__ deg_i,
                         const float* __restrict__ Emb1, const float* __restrict__ Emb2,
                         float* __restrict__ X, int n) {
  int gid = blockIdx.x * blockDim.x + threadIdx.x;
  if (gid >= n * 64) return;
  int node = gid >> 6, l = gid & 63;
  float* xr = X + (size_t)node * XD;
  xr[l] = logits[gid];
  if (l < 16) {
    int dg = deg_i[node]; if (dg > 127) dg = 127;
    xr[96 + l]  = Emb1[dg * 16 + l];
    xr[144 + l] = Emb2[dg * 16 + l];
  }
}

// ---------------- aggregation: Zt = A_hat @ X, stored chunk-major ----------------
// Zt layout: float index ((chunk * n) + node) * 4 + j, chunk = feature/4 (40 chunks)
__global__ __launch_bounds__(256) void k_agg(
    const float* __restrict__ X, float* __restrict__ Zt,
    const int* __restrict__ row_start, const int* __restrict__ srcs,
    const float* __restrict__ coefs, const float* __restrict__ dinv, int n) {
  int w = threadIdx.x >> 6, l = threadIdx.x & 63;
  int node = blockIdx.x * 4 + w;
  if (node >= n) return;
  int beg = row_start[node], end = row_start[node + 1];
  float a0 = 0.f, a1 = 0.f, a2 = 0.f;
  for (int i = beg; i < end; ++i) {
    int s = srcs[i];
    float c = coefs[i];
    const float* xr = X + (size_t)s * XD;
    a0 += c * xr[l];
    a1 += c * xr[64 + l];
    if (l < 32) a2 += c * xr[128 + l];
  }
  float di = dinv[node];
  float c2 = di * di;
  const float* xs = X + (size_t)node * XD;
  a0 += c2 * xs[l];
  a1 += c2 * xs[64 + l];
  if (l < 32) a2 += c2 * xs[128 + l];
  // transposed store: element e -> Zt[(e>>2)*n + node)*4 + (e&3)]
  int ch = l >> 2, j = l & 3;
  Zt[((size_t)ch * n + node) * 4 + j] = a0;                 // e = l
  Zt[((size_t)(16 + ch) * n + node) * 4 + j] = a1;          // e = 64 + l
  if (l < 32) Zt[((size_t)(32 + ch) * n + node) * 4 + j] = a2;  // e = 128 + l
}

// ---------------- final: lane=node, W via uniform scalar loads, comb[64] in VGPRs ---------
__global__ __launch_bounds__(256, 4) void k_final(
    const float* __restrict__ Zt, const float* __restrict__ logits,
    const float* __restrict__ FG, const int* __restrict__ deg_i,
    const float* __restrict__ W0, const float* __restrict__ b0,
    const float* __restrict__ W1, const float* __restrict__ b1,
    const float* __restrict__ W2, const float* __restrict__ b2,
    const float* __restrict__ Embg, const float* __restrict__ wg,
    float* __restrict__ out, int n) {
  int l = threadIdx.x & 63;
  int w = threadIdx.x >> 6;
  int g = blockIdx.x * 4 + w;          // wave id; wave owns nodes [g*64, g*64+64)
  int node = g * 64 + l;
  int nc = node < n ? node : n - 1;

  // ---- gating: clean = [logits | FG | Embg[deg]] @ wg  (wg uniform -> s_load) ----
  float c0 = 0.f, c1 = 0.f, c2 = 0.f;
  const float* lgr = logits + (size_t)nc * 64;
#pragma unroll
  for (int q = 0; q < 16; ++q) {
    float4 v = *(const float4*)&lgr[q * 4];
    const float* p = (const float*)&v;
#pragma unroll
    for (int j = 0; j < 4; ++j) {
      int k = q * 4 + j;
      c0 += p[j] * wg[k * 3 + 0];
      c1 += p[j] * wg[k * 3 + 1];
      c2 += p[j] * wg[k * 3 + 2];
    }
  }
  {
    const float* fgr = FG + (size_t)nc * 32;
#pragma unroll
    for (int q = 0; q < 8; ++q) {
      float4 v = *(const float4*)&fgr[q * 4];
      const float* p = (const float*)&v;
#pragma unroll
      for (int j = 0; j < 4; ++j) {
        int k = 64 + q * 4 + j;
        c0 += p[j] * wg[k * 3 + 0];
        c1 += p[j] * wg[k * 3 + 1];
        c2 += p[j] * wg[k * 3 + 2];
      }
    }
  }
  {
    int dg = deg_i[nc]; if (dg > 127) dg = 127;
    const float* egr = Embg + dg * 16;
#pragma unroll
    for (int q = 0; q < 4; ++q) {
      float4 v = *(const float4*)&egr[q * 4];
      const float* p = (const float*)&v;
#pragma unroll
      for (int j = 0; j < 4; ++j) {
        int k = 96 + q * 4 + j;
        c0 += p[j] * wg[k * 3 + 0];
        c1 += p[j] * wg[k * 3 + 1];
        c2 += p[j] * wg[k * 3 + 2];
      }
    }
  }

  // top-2 of 3 (ties -> lower index, matching lax.top_k), softmax over the 2
  int i0 = 0; float t0 = c0;
  if (c1 > t0) { t0 = c1; i0 = 1; }
  if (c2 > t0) { t0 = c2; i0 = 2; }
  float t1 = -3.4e38f; int i1 = 0;
  if (i0 != 0) { t1 = c0; i1 = 0; }
  if (i0 != 1 && c1 > t1) { t1 = c1; i1 = 1; }
  if (i0 != 2 && c2 > t1) { t1 = c2; i1 = 2; }
  float e1v = expf(t1 - t0);
  float gsum = 1.0f + e1v;
  float gA = 1.0f / gsum, gB = e1v / gsum;
  float g0 = (i0 == 0) ? gA : (i1 == 0) ? gB : 0.f;
  float g1 = (i0 == 1) ? gA : (i1 == 1) ? gB : 0.f;
  float g2 = (i0 == 2) ? gA : (i1 == 2) ? gB : 0.f;

  // ---- experts: comb[c] += g_e * z[k] * W_e[k][c], z chunks gate-prescaled ----
  float comb[64];
#pragma unroll
  for (int c = 0; c < 64; ++c) comb[c] = 0.f;

#define CHUNK(CIDX, GE, WPTR, KROW)                                        \
  {                                                                        \
    float4 zq = *(const float4*)&Zt[((size_t)(CIDX) * n + nc) * 4];        \
    float zs[4] = {(GE) * zq.x, (GE) * zq.y, (GE) * zq.z, (GE) * zq.w};    \
    const float* wr = (WPTR) + (KROW) * 64;                                \
    _Pragma("unroll") for (int kk = 0; kk < 4; ++kk) {                     \
      float zz = zs[kk];                                                   \
      const float* wrow = wr + kk * 64;                                    \
      _Pragma("unroll") for (int c = 0; c < 64; ++c)                       \
        comb[c] += zz * wrow[c];                                           \
    }                                                                      \
  }

  // expert 0: z[0..95] (chunks 0..23) x W0 rows 0..95
  for (int t = 0; t < 24; ++t) CHUNK(t, g0, W0, 4 * t);
  // expert 1: z[0..63] (chunks 0..15) x W1 rows 0..63; z[96..111] (chunks 24..27) x W1 rows 64..79
  for (int t = 0; t < 16; ++t) CHUNK(t, g1, W1, 4 * t);
  for (int t = 0; t < 4; ++t)  CHUNK(24 + t, g1, W1, 64 + 4 * t);
  // expert 2: z[112..159] (chunks 28..39) x W2 rows 0..47
  for (int t = 0; t < 12; ++t) CHUNK(28 + t, g2, W2, 4 * t);
#undef CHUNK

  // bias (uniform -> s_load)
#pragma unroll
  for (int c = 0; c < 64; ++c)
    comb[c] += g0 * b0[c] + g1 * b1[c] + g2 * b2[c];

  // epilogue: out[node][c] = logits[node][c] * softplus(comb[c])
  if (node < n) {
    float4* outr = (float4*)(out + (size_t)node * 64);
#pragma unroll
    for (int q = 0; q < 16; ++q) {
      float4 lg4 = *(const float4*)&lgr[q * 4];
      const float* pl = (const float*)&lg4;
      float4 o;
      float* po = (float*)&o;
#pragma unroll
      for (int j = 0; j < 4; ++j) {
        float v = comb[q * 4 + j];
        float sp = fmaxf(v, 0.f) + log1pf(expf(-fabsf(v)));
        po[j] = pl[j] * sp;
      }
      outr[q] = o;
    }
  }
}

extern "C" void kernel_launch(void* const* d_in, const int* in_sizes, int n_in,
                              void* d_out, int out_size, void* d_ws, size_t ws_size,
                              hipStream_t stream) {
  const float* logits = (const float*)d_in[0];
  const float* feat   = (const float*)d_in[1];
  const int*   ei     = (const int*)d_in[2];
  const float* Wf0 = (const float*)d_in[3];
  const float* bf0 = (const float*)d_in[4];
  const float* W0  = (const float*)d_in[5];
  const float* b0  = (const float*)d_in[6];
  const float* Emb1= (const float*)d_in[7];
  const float* W1  = (const float*)d_in[8];
  const float* b1  = (const float*)d_in[9];
  const float* Wf2 = (const float*)d_in[10];
  const float* bf2 = (const float*)d_in[11];
  const float* Emb2= (const float*)d_in[12];
  const float* W2  = (const float*)d_in[13];
  const float* b2  = (const float*)d_in[14];
  const float* Wfg = (const float*)d_in[15];
  const float* bfg = (const float*)d_in[16];
  const float* Embg= (const float*)d_in[17];
  const float* wg  = (const float*)d_in[18];

  int n = in_sizes[0] / 64;
  int E = in_sizes[2] / 2;

  char* base = (char*)d_ws;
  size_t off = 0;
  auto alloc = [&](size_t bytes) -> void* {
    void* p = base + off;
    off += bytes;
    off = (off + 255) & ~(size_t)255;
    return p;
  };
  int*   deg_i     = (int*)alloc((size_t)n * 4);
  int*   deg_dst   = (int*)alloc((size_t)n * 4);
  int*   cursor    = (int*)alloc((size_t)n * 4);
  size_t zero_bytes = off;                 // deg_i + deg_dst + cursor
  int*   row_start = (int*)alloc(((size_t)n + 1) * 4);
  int*   bsum      = (int*)alloc(1024 * 4);
  float* dinv      = (float*)alloc((size_t)n * 4);
  int*   srcs      = (int*)alloc((size_t)E * 4);
  float* coefs     = (float*)alloc((size_t)E * 4);
  float* FG        = (float*)alloc((size_t)n * 32 * 4);
  float* X         = (float*)alloc((size_t)n * XD * 4);
  float* Zt        = (float*)alloc((size_t)n * XD * 4);
  (void)ws_size;

  hipMemsetAsync(base, 0, zero_bytes, stream);

  int nb_scan = (n + 1023) / 1024;
  k_degrees<<<(E + 255) / 256, 256, 0, stream>>>(ei, E, deg_i, deg_dst);
  k_scan1<<<nb_scan, 1024, 0, stream>>>(deg_dst, n, bsum);
  k_scan2<<<1, 64, 0, stream>>>(bsum, nb_scan, row_start, n);
  k_scan3<<<nb_scan, 1024, 0, stream>>>(deg_dst, n, bsum, row_start, dinv);
  k_proj<<<(n + PBM - 1) / PBM, 256, 0, stream>>>(feat, Wf0, bf0, Wf2, bf2, Wfg, bfg, X, FG, n);
  k_buildx<<<((size_t)n * 64 + 255) / 256, 256, 0, stream>>>(logits, deg_i, Emb1, Emb2, X, n);
  k_fill<<<(E + 255) / 256, 256, 0, stream>>>(ei, E, row_start, cursor, dinv, srcs, coefs);
  k_agg<<<(n + 3) / 4, 256, 0, stream>>>(X, Zt, row_start, srcs, coefs, dinv, n);
  int waves = (n + 63) / 64;
  k_final<<<(waves + 3) / 4, 256, 0, stream>>>(Zt, logits, FG, deg_i, W0, b0, W1, b1, W2, b2,
                                               Embg, wg, (float*)d_out, n);
}

// Round 4
// 841.733 us; speedup vs baseline: 1.6441x; 1.0944x over previous
//
#include <hip/hip_runtime.h>
#include <hip/hip_bf16.h>
#include <math.h>

// GETS calibrator: MoE-GCN. N nodes, E edges, C=64, F=512, FH=32, DH=16.
// R4: k_proj rewritten lane=node, wave=matrix (Wf0/Wf2/Wfg), W via uniform scalar
//     loads (s_load), feat row streamed per-lane, acc[32] in VGPRs, zero LDS.
//     (R3 k_proj was LDS-port-bound: 4 b128 per 48 FMA across 12 waves/CU.)

#define XD 160   // aggregated feature dim
#define CC 64    // classes

// ---------------- degree counting ----------------
__global__ void k_degrees(const int* __restrict__ ei, int E,
                          int* __restrict__ deg_i, int* __restrict__ deg_dst) {
  int e = blockIdx.x * blockDim.x + threadIdx.x;
  if (e >= E) return;
  int s = ei[e], d = ei[E + e];
  atomicAdd(&deg_i[s], 1);
  atomicAdd(&deg_i[d], 1);
  atomicAdd(&deg_dst[d], 1);
}

// ---------------- 2-level exclusive scan of deg_dst -> row_start ----------------
__global__ void k_scan1(const int* __restrict__ deg, int n, int* __restrict__ bsum) {
  __shared__ int red[1024];
  int tid = threadIdx.x;
  int i = blockIdx.x * 1024 + tid;
  red[tid] = (i < n) ? deg[i] : 0;
  __syncthreads();
  for (int s = 512; s > 0; s >>= 1) {
    if (tid < s) red[tid] += red[tid + s];
    __syncthreads();
  }
  if (tid == 0) bsum[blockIdx.x] = red[0];
}

__global__ void k_scan2(int* __restrict__ bsum, int nb, int* __restrict__ row_start, int n) {
  if (threadIdx.x == 0 && blockIdx.x == 0) {
    int run = 0;
    for (int b = 0; b < nb; ++b) { int t = bsum[b]; bsum[b] = run; run += t; }
    row_start[n] = run;   // == E
  }
}

__global__ void k_scan3(const int* __restrict__ deg, int n, const int* __restrict__ bsum,
                        int* __restrict__ row_start, float* __restrict__ dinv) {
  __shared__ int sc[1024];
  int tid = threadIdx.x;
  int i = blockIdx.x * 1024 + tid;
  int v = (i < n) ? deg[i] : 0;
  sc[tid] = v;
  __syncthreads();
  for (int ofs = 1; ofs < 1024; ofs <<= 1) {
    int t = (tid >= ofs) ? sc[tid - ofs] : 0;
    __syncthreads();
    sc[tid] += t;
    __syncthreads();
  }
  if (i < n) {
    int incl = sc[tid];
    row_start[i] = incl - v + bsum[blockIdx.x];
    dinv[i] = rsqrtf((float)v + 1.0f);   // GCN deg = indeg + 1 (self loop)
  }
}

// ---------------- CSR fill (src + precomputed coef per edge) ----------------
__global__ void k_fill(const int* __restrict__ ei, int E, const int* __restrict__ row_start,
                       int* __restrict__ cursor, const float* __restrict__ dinv,
                       int* __restrict__ srcs, float* __restrict__ coefs) {
  int e = blockIdx.x * blockDim.x + threadIdx.x;
  if (e >= E) return;
  int s = ei[e], d = ei[E + e];
  int pos = row_start[d] + atomicAdd(&cursor[d], 1);
  srcs[pos] = s;
  coefs[pos] = dinv[s] * dinv[d];
}

// ---------------- projection: feat(n,512) @ {Wf0,Wf2,Wfg}(512,32) ----------------
// lane = node, wave m = which matrix. W rows are wave-uniform -> s_load (SGPR),
// feat row streamed per-lane via float4 (L1 line reused 4x; waves 1,2 L1-hit wave 0's rows).
__global__ __launch_bounds__(192) void k_proj(
    const float* __restrict__ feat,
    const float* __restrict__ Wf0, const float* __restrict__ bf0,
    const float* __restrict__ Wf2, const float* __restrict__ bf2,
    const float* __restrict__ Wfg, const float* __restrict__ bfg,
    float* __restrict__ X, float* __restrict__ FG, int n) {
  int l = threadIdx.x & 63;
  int m = __builtin_amdgcn_readfirstlane(threadIdx.x >> 6);   // wave-uniform matrix id
  int node = blockIdx.x * 64 + l;
  int nc = node < n ? node : n - 1;
  const float* fr = feat + (size_t)nc * 512;

  const float* Wm;
  const float* bm;
  if (m == 0)      { Wm = Wf0; bm = bf0; }
  else if (m == 1) { Wm = Wf2; bm = bf2; }
  else             { Wm = Wfg; bm = bfg; }

  float acc[32];
#pragma unroll
  for (int c = 0; c < 32; ++c) acc[c] = 0.f;

  for (int kq = 0; kq < 128; ++kq) {
    float4 f4 = *(const float4*)&fr[kq * 4];
    const float* p = (const float*)&f4;
#pragma unroll
    for (int j = 0; j < 4; ++j) {
      float fv = p[j];
      const float* wr = Wm + (kq * 4 + j) * 32;   // uniform address -> s_load
#pragma unroll
      for (int c = 0; c < 32; ++c) acc[c] += fv * wr[c];
    }
  }

  if (node < n) {
    // add bias (uniform), store 32 floats as 8 float4
    float ov[32];
#pragma unroll
    for (int c = 0; c < 32; ++c) ov[c] = acc[c] + bm[c];
    float* dst;
    if (m == 0)      dst = X + (size_t)node * XD + 64;    // f0
    else if (m == 1) dst = X + (size_t)node * XD + 112;   // f2
    else             dst = FG + (size_t)node * 32;        // gating proj
#pragma unroll
    for (int q = 0; q < 8; ++q)
      *(float4*)&dst[q * 4] = *(const float4*)&ov[q * 4];
  }
}

// ---------------- build X: logits copy + degree embeddings ----------------
__global__ void k_buildx(const float* __restrict__ logits, const int* __restrict__ deg_i,
                         const float* __restrict__ Emb1, const float* __restrict__ Emb2,
                         float* __restrict__ X, int n) {
  int gid = blockIdx.x * blockDim.x + threadIdx.x;
  if (gid >= n * 64) return;
  int node = gid >> 6, l = gid & 63;
  float* xr = X + (size_t)node * XD;
  xr[l] = logits[gid];
  if (l < 16) {
    int dg = deg_i[node]; if (dg > 127) dg = 127;
    xr[96 + l]  = Emb1[dg * 16 + l];
    xr[144 + l] = Emb2[dg * 16 + l];
  }
}

// ---------------- aggregation: Zt = A_hat @ X, stored chunk-major ----------------
// Zt layout: float index ((chunk * n) + node) * 4 + j, chunk = feature/4 (40 chunks)
__global__ __launch_bounds__(256) void k_agg(
    const float* __restrict__ X, float* __restrict__ Zt,
    const int* __restrict__ row_start, const int* __restrict__ srcs,
    const float* __restrict__ coefs, const float* __restrict__ dinv, int n) {
  int w = threadIdx.x >> 6, l = threadIdx.x & 63;
  int node = blockIdx.x * 4 + w;
  if (node >= n) return;
  int beg = row_start[node], end = row_start[node + 1];
  float a0 = 0.f, a1 = 0.f, a2 = 0.f;
  for (int i = beg; i < end; ++i) {
    int s = srcs[i];
    float c = coefs[i];
    const float* xr = X + (size_t)s * XD;
    a0 += c * xr[l];
    a1 += c * xr[64 + l];
    if (l < 32) a2 += c * xr[128 + l];
  }
  float di = dinv[node];
  float c2 = di * di;
  const float* xs = X + (size_t)node * XD;
  a0 += c2 * xs[l];
  a1 += c2 * xs[64 + l];
  if (l < 32) a2 += c2 * xs[128 + l];
  int ch = l >> 2, j = l & 3;
  Zt[((size_t)ch * n + node) * 4 + j] = a0;
  Zt[((size_t)(16 + ch) * n + node) * 4 + j] = a1;
  if (l < 32) Zt[((size_t)(32 + ch) * n + node) * 4 + j] = a2;
}

// ---------------- final: lane=node, W via uniform scalar loads, comb[64] in VGPRs ---------
__global__ __launch_bounds__(256, 4) void k_final(
    const float* __restrict__ Zt, const float* __restrict__ logits,
    const float* __restrict__ FG, const int* __restrict__ deg_i,
    const float* __restrict__ W0, const float* __restrict__ b0,
    const float* __restrict__ W1, const float* __restrict__ b1,
    const float* __restrict__ W2, const float* __restrict__ b2,
    const float* __restrict__ Embg, const float* __restrict__ wg,
    float* __restrict__ out, int n) {
  int l = threadIdx.x & 63;
  int w = threadIdx.x >> 6;
  int g = blockIdx.x * 4 + w;
  int node = g * 64 + l;
  int nc = node < n ? node : n - 1;

  // ---- gating ----
  float c0 = 0.f, c1 = 0.f, c2 = 0.f;
  const float* lgr = logits + (size_t)nc * 64;
#pragma unroll
  for (int q = 0; q < 16; ++q) {
    float4 v = *(const float4*)&lgr[q * 4];
    const float* p = (const float*)&v;
#pragma unroll
    for (int j = 0; j < 4; ++j) {
      int k = q * 4 + j;
      c0 += p[j] * wg[k * 3 + 0];
      c1 += p[j] * wg[k * 3 + 1];
      c2 += p[j] * wg[k * 3 + 2];
    }
  }
  {
    const float* fgr = FG + (size_t)nc * 32;
#pragma unroll
    for (int q = 0; q < 8; ++q) {
      float4 v = *(const float4*)&fgr[q * 4];
      const float* p = (const float*)&v;
#pragma unroll
      for (int j = 0; j < 4; ++j) {
        int k = 64 + q * 4 + j;
        c0 += p[j] * wg[k * 3 + 0];
        c1 += p[j] * wg[k * 3 + 1];
        c2 += p[j] * wg[k * 3 + 2];
      }
    }
  }
  {
    int dg = deg_i[nc]; if (dg > 127) dg = 127;
    const float* egr = Embg + dg * 16;
#pragma unroll
    for (int q = 0; q < 4; ++q) {
      float4 v = *(const float4*)&egr[q * 4];
      const float* p = (const float*)&v;
#pragma unroll
      for (int j = 0; j < 4; ++j) {
        int k = 96 + q * 4 + j;
        c0 += p[j] * wg[k * 3 + 0];
        c1 += p[j] * wg[k * 3 + 1];
        c2 += p[j] * wg[k * 3 + 2];
      }
    }
  }

  int i0 = 0; float t0 = c0;
  if (c1 > t0) { t0 = c1; i0 = 1; }
  if (c2 > t0) { t0 = c2; i0 = 2; }
  float t1 = -3.4e38f; int i1 = 0;
  if (i0 != 0) { t1 = c0; i1 = 0; }
  if (i0 != 1 && c1 > t1) { t1 = c1; i1 = 1; }
  if (i0 != 2 && c2 > t1) { t1 = c2; i1 = 2; }
  float e1v = expf(t1 - t0);
  float gsum = 1.0f + e1v;
  float gA = 1.0f / gsum, gB = e1v / gsum;
  float g0 = (i0 == 0) ? gA : (i1 == 0) ? gB : 0.f;
  float g1 = (i0 == 1) ? gA : (i1 == 1) ? gB : 0.f;
  float g2 = (i0 == 2) ? gA : (i1 == 2) ? gB : 0.f;

  float comb[64];
#pragma unroll
  for (int c = 0; c < 64; ++c) comb[c] = 0.f;

#define CHUNK(CIDX, GE, WPTR, KROW)                                        \
  {                                                                        \
    float4 zq = *(const float4*)&Zt[((size_t)(CIDX) * n + nc) * 4];        \
    float zs[4] = {(GE) * zq.x, (GE) * zq.y, (GE) * zq.z, (GE) * zq.w};    \
    const float* wr = (WPTR) + (KROW) * 64;                                \
    _Pragma("unroll") for (int kk = 0; kk < 4; ++kk) {                     \
      float zz = zs[kk];                                                   \
      const float* wrow = wr + kk * 64;                                    \
      _Pragma("unroll") for (int c = 0; c < 64; ++c)                       \
        comb[c] += zz * wrow[c];                                           \
    }                                                                      \
  }

  for (int t = 0; t < 24; ++t) CHUNK(t, g0, W0, 4 * t);
  for (int t = 0; t < 16; ++t) CHUNK(t, g1, W1, 4 * t);
  for (int t = 0; t < 4; ++t)  CHUNK(24 + t, g1, W1, 64 + 4 * t);
  for (int t = 0; t < 12; ++t) CHUNK(28 + t, g2, W2, 4 * t);
#undef CHUNK

#pragma unroll
  for (int c = 0; c < 64; ++c)
    comb[c] += g0 * b0[c] + g1 * b1[c] + g2 * b2[c];

  if (node < n) {
    float4* outr = (float4*)(out + (size_t)node * 64);
#pragma unroll
    for (int q = 0; q < 16; ++q) {
      float4 lg4 = *(const float4*)&lgr[q * 4];
      const float* pl = (const float*)&lg4;
      float4 o;
      float* po = (float*)&o;
#pragma unroll
      for (int j = 0; j < 4; ++j) {
        float v = comb[q * 4 + j];
        float sp = fmaxf(v, 0.f) + log1pf(expf(-fabsf(v)));
        po[j] = pl[j] * sp;
      }
      outr[q] = o;
    }
  }
}

extern "C" void kernel_launch(void* const* d_in, const int* in_sizes, int n_in,
                              void* d_out, int out_size, void* d_ws, size_t ws_size,
                              hipStream_t stream) {
  const float* logits = (const float*)d_in[0];
  const float* feat   = (const float*)d_in[1];
  const int*   ei     = (const int*)d_in[2];
  const float* Wf0 = (const float*)d_in[3];
  const float* bf0 = (const float*)d_in[4];
  const float* W0  = (const float*)d_in[5];
  const float* b0  = (const float*)d_in[6];
  const float* Emb1= (const float*)d_in[7];
  const float* W1  = (const float*)d_in[8];
  const float* b1  = (const float*)d_in[9];
  const float* Wf2 = (const float*)d_in[10];
  const float* bf2 = (const float*)d_in[11];
  const float* Emb2= (const float*)d_in[12];
  const float* W2  = (const float*)d_in[13];
  const float* b2  = (const float*)d_in[14];
  const float* Wfg = (const float*)d_in[15];
  const float* bfg = (const float*)d_in[16];
  const float* Embg= (const float*)d_in[17];
  const float* wg  = (const float*)d_in[18];

  int n = in_sizes[0] / 64;
  int E = in_sizes[2] / 2;

  char* base = (char*)d_ws;
  size_t off = 0;
  auto alloc = [&](size_t bytes) -> void* {
    void* p = base + off;
    off += bytes;
    off = (off + 255) & ~(size_t)255;
    return p;
  };
  int*   deg_i     = (int*)alloc((size_t)n * 4);
  int*   deg_dst   = (int*)alloc((size_t)n * 4);
  int*   cursor    = (int*)alloc((size_t)n * 4);
  size_t zero_bytes = off;                 // deg_i + deg_dst + cursor
  int*   row_start = (int*)alloc(((size_t)n + 1) * 4);
  int*   bsum      = (int*)alloc(1024 * 4);
  float* dinv      = (float*)alloc((size_t)n * 4);
  int*   srcs      = (int*)alloc((size_t)E * 4);
  float* coefs     = (float*)alloc((size_t)E * 4);
  float* FG        = (float*)alloc((size_t)n * 32 * 4);
  float* X         = (float*)alloc((size_t)n * XD * 4);
  float* Zt        = (float*)alloc((size_t)n * XD * 4);
  (void)ws_size;

  hipMemsetAsync(base, 0, zero_bytes, stream);

  int nb_scan = (n + 1023) / 1024;
  k_degrees<<<(E + 255) / 256, 256, 0, stream>>>(ei, E, deg_i, deg_dst);
  k_scan1<<<nb_scan, 1024, 0, stream>>>(deg_dst, n, bsum);
  k_scan2<<<1, 64, 0, stream>>>(bsum, nb_scan, row_start, n);
  k_scan3<<<nb_scan, 1024, 0, stream>>>(deg_dst, n, bsum, row_start, dinv);
  k_proj<<<(n + 63) / 64, 192, 0, stream>>>(feat, Wf0, bf0, Wf2, bf2, Wfg, bfg, X, FG, n);
  k_buildx<<<((size_t)n * 64 + 255) / 256, 256, 0, stream>>>(logits, deg_i, Emb1, Emb2, X, n);
  k_fill<<<(E + 255) / 256, 256, 0, stream>>>(ei, E, row_start, cursor, dinv, srcs, coefs);
  k_agg<<<(n + 3) / 4, 256, 0, stream>>>(X, Zt, row_start, srcs, coefs, dinv, n);
  int waves = (n + 63) / 64;
  k_final<<<(waves + 3) / 4, 256, 0, stream>>>(Zt, logits, FG, deg_i, W0, b0, W1, b1, W2, b2,
                                               Embg, wg, (float*)d_out, n);
}